// Round 12
// baseline (122.477 us; speedup 1.0000x reference)
//
#include <hip/hip_runtime.h>

// Problem dims (fixed by reference setup_inputs)
#define B_  4
#define C_  3
#define S_  5
#define M_  18
#define HW  45056            // 256*176
#define HW4 (HW/4)           // 11264 float4s per plane/channel
#define SPLIT 4              // blocks per (b,s,m) plane (divides HW4/TPB = 44)
#define TPB 256
#define CHUNK4 (HW4/SPLIT)   // 2816 float4s per block
#define ITERS (CHUNK4/TPB)   // 11 iterations per thread
#define NPLANE (B_*S_*M_)    // 360
#define NBLK (NPLANE*SPLIT)  // 1440 blocks (1440 % 8 == 0 -> bijective XCD swizzle)

// ============================= DESIGN LEDGER =============================
// Champion config (R6, 116.4us wall). Exact revert — every deviation lost:
//  - nt on mask: +8.5us (R9 clean A/B; forfeits post-restore L3 residency)
//  - mask reg-staging (11x float4): +8us (R7; VGPR 88->occupancy loss)
//  - __launch_bounds__(256,8): VGPR 32 -> accumulator spills, 305MB
//    scratch, +130us (R8). Never force VGPR below ~64 here.
//  - depth-2 mask prefetch ring: +4us (R11; displaces compiler schedule)
//  - G-share via registers (R1/R2) or L1-lockstep groups (R10): +8-10us
//    (fewer waves / extra barriers; FETCH unchanged — no L1 win)
//  - LDS-transpose block reduce: no win at ITERS=11 (R3)
//  - flag-fused single kernel: release fences = buffer_wbl2 storm (R4,
//    45us all-idle); relaxed sc1 = scalar un-vectorizable coherence loads
//    (R5, 70us). Kernel boundary does the coherence once, ~free.
// Counter triangulation (R4/R7/R10): moments is LATENCY-bound (HBM<=12%,
// VALU<=23%, Occ 17-26%), insensitive to placement/occupancy/scheduling;
// all-cached rocprof replay runs at the same duration. hipcc's schedule of
// the interleaved 7-stream loop is the local optimum at HIP level.
// Wall accounting: ~84us harness (268MB ws poison fill + 65MB mask restore
// copy, HBM-write-bound) + ~27us moments + ~4us finalize + gaps ~= 116us.
// =========================================================================

// Kernel A: per-(plane,chunk) partial sums of the 16 weighted RAW moments.
// Rescale is deferred to the epilogue (exact affine transform in double).
__global__ __launch_bounds__(TPB) void moments_kernel(
    const float4* __restrict__ X, const float4* __restrict__ Y,
    const float4* __restrict__ Mk, float* __restrict__ part) {
  // XCD-aware bijective swizzle: each XCD's L2 holds ~1 batch of X/Y.
  int wg    = (blockIdx.x & 7) * (NBLK / 8) + (blockIdx.x >> 3);
  int plane = wg / SPLIT;           // (b,s,m)
  int chunk = wg - plane * SPLIT;
  int b     = plane / (S_ * M_);

  const float4* mp = Mk + (size_t)plane * HW4;
  const float4* xp = X  + (size_t)b * (C_ * HW4);
  const float4* yp = Y  + (size_t)b * (C_ * HW4);

  int base = chunk * CHUNK4 + (int)threadIdx.x;

  float aW = 0.f;
  float a1[C_], a2[C_], a11[C_], a22[C_], a12[C_];
#pragma unroll
  for (int c = 0; c < C_; ++c) { a1[c]=a2[c]=a11[c]=a22[c]=a12[c]=0.f; }

#pragma unroll
  for (int it = 0; it < ITERS; ++it) {
    int i = base + it * TPB;
    // Plain cached loads; interleaved 7-stream loop; compiler-scheduled.
    float4 w  = mp[i];
    aW += (w.x + w.y) + (w.z + w.w);
    float wf[4] = {w.x, w.y, w.z, w.w};
#pragma unroll
    for (int c = 0; c < C_; ++c) {
      float4 xv = xp[c * HW4 + i];
      float4 yv = yp[c * HW4 + i];
      float xf[4] = {xv.x, xv.y, xv.z, xv.w};
      float yf[4] = {yv.x, yv.y, yv.z, yv.w};
#pragma unroll
      for (int j = 0; j < 4; ++j) {
        float xc = xf[j], yc = yf[j], wc = wf[j];
        float wx = wc * xc;
        float wy = wc * yc;
        a1 [c] += wx;
        a2 [c] += wy;
        a11[c]  = fmaf(wx, xc, a11[c]);
        a22[c]  = fmaf(wy, yc, a22[c]);
        a12[c]  = fmaf(wx, yc, a12[c]);
      }
    }
  }

  // Pack 16 values: [0]=msum, then per channel {wx, wy, wxx, wyy, wxy} (raw)
  float v[16];
  v[0] = aW;
#pragma unroll
  for (int c = 0; c < C_; ++c) {
    v[1 + c*5 + 0] = a1[c];
    v[1 + c*5 + 1] = a2[c];
    v[1 + c*5 + 2] = a11[c];
    v[1 + c*5 + 3] = a22[c];
    v[1 + c*5 + 4] = a12[c];
  }

  // wave-64 butterfly reduce (amortized over the 11-iter main loop)
#pragma unroll
  for (int off = 32; off > 0; off >>= 1) {
#pragma unroll
    for (int j = 0; j < 16; ++j) v[j] += __shfl_xor(v[j], off);
  }

  __shared__ float red[TPB/64][16];
  int lane = threadIdx.x & 63;
  int wv   = threadIdx.x >> 6;
  if (lane == 0) {
#pragma unroll
    for (int j = 0; j < 16; ++j) red[wv][j] = v[j];
  }
  __syncthreads();
  if (threadIdx.x < 16) {
    float s = (red[0][threadIdx.x] + red[1][threadIdx.x]) +
              (red[2][threadIdx.x] + red[3][threadIdx.x]);
    part[(size_t)wg * 16 + threadIdx.x] = s;
  }
}

// Kernel B: tiny epilogue, one block. Plain loads (kernel-boundary coherence).
// Exact affine rescale of raw moments in double:
//   xs = 0.5x + 0.5  =>  E[w*xs]    = 0.5*S1 + 0.5*W
//                        E[w*xs^2]  = 0.25*S11 + 0.5*S1 + 0.25*W
//                        E[w*xs*ys] = 0.25*(S12 + S1 + S2 + W)
__global__ __launch_bounds__(384) void finalize_kernel(
    const float* __restrict__ part, float* __restrict__ out) {
  __shared__ float csS[NPLANE], ssS[NPLANE];
  __shared__ double csb[B_*S_], ssb[B_*S_];
  int t = threadIdx.x;

  if (t < NPLANE) {
    double s[16];
#pragma unroll
    for (int j = 0; j < 16; ++j) s[j] = 0.0;
    for (int ch = 0; ch < SPLIT; ++ch) {
      const float* p = part + (size_t)(t * SPLIT + ch) * 16;
#pragma unroll
      for (int j = 0; j < 16; ++j) s[j] += (double)p[j];
    }
    const double C1d = 1e-4, C2d = 9e-4;
    double W = s[0];
    double inv = 1.0 / (W + 1e-6);
    double csAcc = 0.0, ssAcc = 0.0;
#pragma unroll
    for (int c = 0; c < C_; ++c) {
      double S1  = s[1 + c*5 + 0];
      double S2  = s[1 + c*5 + 1];
      double S11 = s[1 + c*5 + 2];
      double S22 = s[1 + c*5 + 3];
      double S12 = s[1 + c*5 + 4];
      double mu1  = (0.5*S1 + 0.5*W) * inv;
      double mu2  = (0.5*S2 + 0.5*W) * inv;
      double mu11 = (0.25*S11 + 0.5*S1 + 0.25*W) * inv;
      double mu22 = (0.25*S22 + 0.5*S2 + 0.25*W) * inv;
      double mu12 = (0.25*(S12 + S1 + S2 + W)) * inv;
      double m1s = mu1*mu1, m2s = mu2*mu2, m12 = mu1*mu2;
      double sig1  = mu11 - m1s;
      double sig2  = mu22 - m2s;
      double sig12 = mu12 - m12;
      double cs   = (2.0*sig12 + C2d) / (sig1 + sig2 + C2d);
      double ssim = (2.0*m12 + C1d) / (m1s + m2s + C1d) * cs;
      if (cs   < 0.0) cs   = 0.0;
      if (ssim < 0.0) ssim = 0.0;
      csAcc += cs; ssAcc += ssim;
    }
    csS[t] = (float)csAcc;
    ssS[t] = (float)ssAcc;
  }
  __syncthreads();

  if (t < B_*S_) {  // t = b*S_ + s
    double cb = 0.0, sb = 0.0;
    for (int m = 0; m < M_; ++m) { cb += (double)csS[t*M_ + m]; sb += (double)ssS[t*M_ + m]; }
    csb[t] = cb / (double)(M_*C_);
    ssb[t] = sb / (double)(M_*C_);
  }
  __syncthreads();

  if (t == 0) {
    double acc = 0.0;
    for (int b = 0; b < B_; ++b) {
      double p = ssb[b*S_ + (S_-1)];
      for (int s = 0; s < S_-1; ++s) p *= csb[b*S_ + s];
      acc += p;
    }
    out[0] = (float)(acc / (double)B_);
  }
}

extern "C" void kernel_launch(void* const* d_in, const int* in_sizes, int n_in,
                              void* d_out, int out_size, void* d_ws, size_t ws_size,
                              hipStream_t stream) {
  (void)in_sizes; (void)n_in; (void)out_size; (void)ws_size;
  const float4* X  = (const float4*)d_in[0];
  const float4* Y  = (const float4*)d_in[1];
  const float4* Mk = (const float4*)d_in[2];
  float* part = (float*)d_ws;        // 1440*16*4 = 92160 B
  float* out  = (float*)d_out;

  hipLaunchKernelGGL(moments_kernel, dim3(NBLK), dim3(TPB), 0, stream,
                     X, Y, Mk, part);
  hipLaunchKernelGGL(finalize_kernel, dim3(1), dim3(384), 0, stream, part, out);
}